// Round 4
// baseline (1561.863 us; speedup 1.0000x reference)
//
#include <hip/hip_runtime.h>

#define D     12
#define EPB   4096   // edges per block for passes A/B
#define ABLK  256
#define SBLK  256
#define CBLK  256
#define SPLIT 8      // blocks per bucket in pass C

// ---------------- pass A: per-block bucket histogram ----------------
__global__ __launch_bounds__(ABLK) void passA_hist(
    const int* __restrict__ receivers, long E, int nbuck,
    int* __restrict__ cnt /* [nblk][nbuck], row-major */)
{
    extern __shared__ int hist[]; // nbuck ints
    for (int i = threadIdx.x; i < nbuck; i += ABLK) hist[i] = 0;
    __syncthreads();
    long e0 = (long)blockIdx.x * EPB;
    long e1 = e0 + EPB; if (e1 > E) e1 = E;
    for (long e = e0 + threadIdx.x; e < e1; e += ABLK) {
        int r = receivers[e];
        atomicAdd(&hist[r >> 7], 1);
    }
    __syncthreads();
    int* row = cnt + (long)blockIdx.x * nbuck;
    for (int i = threadIdx.x; i < nbuck; i += ABLK) row[i] = hist[i];
}

// ---------------- pass S1: exclusive scan down each bucket column ----------------
__global__ __launch_bounds__(SBLK) void passS1_colscan(
    int* __restrict__ cnt, int nblk, int nbuck, int* __restrict__ totals)
{
    int b = blockIdx.x;
    int t = threadIdx.x;
    __shared__ int csum[SBLK];
    int per = (nblk + SBLK - 1) / SBLK;
    int i0 = t * per;
    int i1 = i0 + per; if (i1 > nblk) i1 = nblk;
    int s = 0;
    for (int i = i0; i < i1; ++i) s += cnt[(long)i * nbuck + b];
    csum[t] = s;
    __syncthreads();
    for (int off = 1; off < SBLK; off <<= 1) {
        int add = (t >= off) ? csum[t - off] : 0;
        __syncthreads();
        csum[t] += add;
        __syncthreads();
    }
    int run = csum[t] - s; // exclusive prefix of this thread's chunk
    for (int i = i0; i < i1; ++i) {
        long a = (long)i * nbuck + b;
        int tmp = cnt[a];
        cnt[a] = run;
        run += tmp;
    }
    if (t == SBLK - 1) totals[b] = csum[SBLK - 1];
}

// ---------------- pass S2: exclusive scan over bucket totals ----------------
__global__ __launch_bounds__(1024) void passS2_basescan(
    const int* __restrict__ totals, int* __restrict__ base, int nbuck)
{
    __shared__ int sh[1024];
    int t = threadIdx.x;
    int v = (t < nbuck) ? totals[t] : 0;
    sh[t] = v;
    __syncthreads();
    for (int off = 1; off < 1024; off <<= 1) {
        int add = (t >= off) ? sh[t - off] : 0;
        __syncthreads();
        sh[t] += add;
        __syncthreads();
    }
    if (t < nbuck) base[t] = sh[t] - v;
}

// ---------------- pass B: scatter edge ids into bucket-sorted order ----------------
__global__ __launch_bounds__(ABLK) void passB_scatter(
    const int* __restrict__ receivers, long E, int nbuck,
    const int* __restrict__ cnt, const int* __restrict__ base,
    unsigned int* __restrict__ sorted)
{
    extern __shared__ int cur[]; // nbuck cursors
    const int* row = cnt + (long)blockIdx.x * nbuck;
    for (int i = threadIdx.x; i < nbuck; i += ABLK) cur[i] = row[i] + base[i];
    __syncthreads();
    long e0 = (long)blockIdx.x * EPB;
    long e1 = e0 + EPB; if (e1 > E) e1 = E;
    for (long e = e0 + threadIdx.x; e < e1; e += ABLK) {
        int r = receivers[e];
        int b = r >> 7;
        int pos = atomicAdd(&cur[b], 1);
        sorted[pos] = ((unsigned)e << 7) | (unsigned)(r & 127);
    }
}

// -------- shared helper: build folded weights into LDS --------
__device__ __forceinline__ void build_weights(
    int t,
    const float* __restrict__ bn_scale, const float* __restrict__ bn_bias,
    const float* __restrict__ bn_mean,  const float* __restrict__ bn_var,
    const float* __restrict__ W1, const float* __restrict__ b1,
    const float* __restrict__ W2, const float* __restrict__ b2,
    float* sW1, float* sW2, float* sB1, float* sB2)
{
    if (t < D * D) {
        int d = t / D;
        float a = bn_scale[d] * rsqrtf(bn_var[d] + 1e-5f);
        sW1[t] = a * W1[t];
        sW2[t] = W2[t];
    }
    if (t < D) {
        float acc = b1[t];
        #pragma unroll
        for (int d = 0; d < D; ++d) {
            float a = bn_scale[d] * rsqrtf(bn_var[d] + 1e-5f);
            float c = bn_bias[d] - bn_mean[d] * a;
            acc += c * W1[d * D + t];
        }
        sB1[t] = acc;
        sB2[t] = b2[t];
    }
}

__device__ __forceinline__ void mlp_accum(
    const float x[D], int rloc,
    const float* sW1, const float* sW2, const float* sB1, const float* sB2,
    float* acc)
{
    float h[D];
    #pragma unroll
    for (int j = 0; j < D; ++j) h[j] = sB1[j];
    #pragma unroll
    for (int d = 0; d < D; ++d) {
        float xd = x[d];
        #pragma unroll
        for (int j = 0; j < D; ++j) h[j] = fmaf(xd, sW1[d * D + j], h[j]);
    }
    #pragma unroll
    for (int j = 0; j < D; ++j) h[j] = fmaxf(h[j], 0.f);

    float y[D];
    #pragma unroll
    for (int j = 0; j < D; ++j) y[j] = sB2[j];
    #pragma unroll
    for (int d = 0; d < D; ++d) {
        float hd = h[d];
        #pragma unroll
        for (int j = 0; j < D; ++j) y[j] = fmaf(hd, sW2[d * D + j], y[j]);
    }
    #pragma unroll
    for (int j = 0; j < D; ++j) atomicAdd(&acc[rloc * D + j], y[j]);
}

// ---------------- pass C: per-(bucket,split) gather + fused MLP + LDS reduce ----------------
// Writes a full 1536-float slab: to partials (S>1) or directly to out (S==1).
__global__ __launch_bounds__(CBLK, 4) void passC_gather(
    const float* __restrict__ edges,
    const unsigned int* __restrict__ sorted,
    const int* __restrict__ base, const int* __restrict__ totals,
    const float* __restrict__ bn_scale, const float* __restrict__ bn_bias,
    const float* __restrict__ bn_mean,  const float* __restrict__ bn_var,
    const float* __restrict__ W1, const float* __restrict__ b1,
    const float* __restrict__ W2, const float* __restrict__ b2,
    float* __restrict__ part,   // null => write out directly
    float* __restrict__ out,
    long total /* N*D */, long slab /* floats per split */)
{
    __shared__ float sW1[D * D];
    __shared__ float sW2[D * D];
    __shared__ float sB1[D];
    __shared__ float sB2[D];
    __shared__ float acc[128 * D];

    const int t = threadIdx.x;
    build_weights(t, bn_scale, bn_bias, bn_mean, bn_var, W1, b1, W2, b2,
                  sW1, sW2, sB1, sB2);
    for (int i = t; i < 128 * D; i += CBLK) acc[i] = 0.f;
    __syncthreads();

    const int b = blockIdx.x;
    const int s = blockIdx.y;
    const int S = gridDim.y;
    const int s0 = base[b];
    const int n  = totals[b];
    const int chunk = (n + S - 1) / S;
    const int k0 = s * chunk;
    int k1 = k0 + chunk; if (k1 > n) k1 = n;

    for (int k = k0 + 2 * t; k < k1; k += 2 * CBLK) {
        // issue both gathers up front for MLP latency hiding
        unsigned va = sorted[s0 + k];
        bool hasB = (k + 1 < k1);
        unsigned vb = hasB ? sorted[s0 + k + 1] : va;

        long ia = (long)(va >> 7);
        long ib = (long)(vb >> 7);
        const float4* pa = reinterpret_cast<const float4*>(edges + ia * D);
        const float4* pb = reinterpret_cast<const float4*>(edges + ib * D);
        float4 a0 = pa[0], a1 = pa[1], a2 = pa[2];
        float4 b0 = pb[0], b1v = pb[1], b2v = pb[2];

        float xa[D] = {a0.x, a0.y, a0.z, a0.w, a1.x, a1.y, a1.z, a1.w,
                       a2.x, a2.y, a2.z, a2.w};
        mlp_accum(xa, (int)(va & 127u), sW1, sW2, sB1, sB2, acc);

        if (hasB) {
            float xb[D] = {b0.x, b0.y, b0.z, b0.w, b1v.x, b1v.y, b1v.z, b1v.w,
                           b2v.x, b2v.y, b2v.z, b2v.w};
            mlp_accum(xb, (int)(vb & 127u), sW1, sW2, sB1, sB2, acc);
        }
    }
    __syncthreads();

    if (part != nullptr) {
        float* dst = part + (long)s * slab + (long)b * (128 * D);
        for (int i = t; i < 128 * D; i += CBLK) dst[i] = acc[i];
    } else {
        long obase = (long)b * (128 * D);
        long cnt_w = total - obase; if (cnt_w > 128 * D) cnt_w = 128 * D;
        for (long i = t; i < cnt_w; i += CBLK) out[obase + i] = acc[i];
    }
}

// ---------------- reduce: sum SPLIT partial slabs (float4) ----------------
__global__ __launch_bounds__(CBLK) void reduce_partials(
    const float* __restrict__ part, float* __restrict__ out,
    long total4 /* total/4 */, long slab4 /* slab/4 */, int S)
{
    long i = (long)blockIdx.x * CBLK + threadIdx.x;
    if (i >= total4) return;
    const float4* p = reinterpret_cast<const float4*>(part);
    float4 v = p[i];
    for (int s = 1; s < S; ++s) {
        float4 w = p[(long)s * slab4 + i];
        v.x += w.x; v.y += w.y; v.z += w.z; v.w += w.w;
    }
    reinterpret_cast<float4*>(out)[i] = v;
}

// ---------------- fallback: direct atomic scatter (round-1 kernel) ----------------
#define EPT 4
__global__ __launch_bounds__(ABLK) void edge_mlp_scatter(
    const float* __restrict__ edges,
    const float* __restrict__ bn_scale, const float* __restrict__ bn_bias,
    const float* __restrict__ bn_mean,  const float* __restrict__ bn_var,
    const float* __restrict__ W1, const float* __restrict__ b1,
    const float* __restrict__ W2, const float* __restrict__ b2,
    const int* __restrict__ receivers, float* __restrict__ out, long E)
{
    __shared__ float sW1[D * D], sW2[D * D], sB1[D], sB2[D];
    const int t = threadIdx.x;
    build_weights(t, bn_scale, bn_bias, bn_mean, bn_var, W1, b1, W2, b2,
                  sW1, sW2, sB1, sB2);
    __syncthreads();
    const long basee = (long)blockIdx.x * (ABLK * EPT) + t;
    float x[EPT][D]; int rcv[EPT]; bool valid[EPT];
    #pragma unroll
    for (int k = 0; k < EPT; ++k) {
        long e = basee + (long)k * ABLK;
        valid[k] = (e < E); rcv[k] = 0;
        if (valid[k]) {
            rcv[k] = receivers[e];
            const float4* p = reinterpret_cast<const float4*>(edges + e * D);
            float4 v0 = p[0], v1 = p[1], v2 = p[2];
            x[k][0]=v0.x; x[k][1]=v0.y; x[k][2]=v0.z; x[k][3]=v0.w;
            x[k][4]=v1.x; x[k][5]=v1.y; x[k][6]=v1.z; x[k][7]=v1.w;
            x[k][8]=v2.x; x[k][9]=v2.y; x[k][10]=v2.z; x[k][11]=v2.w;
        } else {
            #pragma unroll
            for (int d = 0; d < D; ++d) x[k][d] = 0.f;
        }
    }
    float h[EPT][D];
    #pragma unroll
    for (int j = 0; j < D; ++j) {
        float bj = sB1[j];
        #pragma unroll
        for (int k = 0; k < EPT; ++k) h[k][j] = bj;
    }
    #pragma unroll
    for (int d = 0; d < D; ++d) {
        #pragma unroll
        for (int j = 0; j < D; ++j) {
            float w = sW1[d * D + j];
            #pragma unroll
            for (int k = 0; k < EPT; ++k) h[k][j] = fmaf(x[k][d], w, h[k][j]);
        }
    }
    #pragma unroll
    for (int j = 0; j < D; ++j) {
        #pragma unroll
        for (int k = 0; k < EPT; ++k) h[k][j] = fmaxf(h[k][j], 0.f);
    }
    #pragma unroll
    for (int j = 0; j < D; ++j) {
        float a2[EPT]; float bj = sB2[j];
        #pragma unroll
        for (int k = 0; k < EPT; ++k) a2[k] = bj;
        #pragma unroll
        for (int d = 0; d < D; ++d) {
            float w = sW2[d * D + j];
            #pragma unroll
            for (int k = 0; k < EPT; ++k) a2[k] = fmaf(h[k][d], w, a2[k]);
        }
        #pragma unroll
        for (int k = 0; k < EPT; ++k)
            if (valid[k]) atomicAdd(&out[(long)rcv[k] * D + j], a2[k]);
    }
}

extern "C" void kernel_launch(void* const* d_in, const int* in_sizes, int n_in,
                              void* d_out, int out_size, void* d_ws, size_t ws_size,
                              hipStream_t stream) {
    const float* edges     = (const float*)d_in[0];
    const float* bn_scale  = (const float*)d_in[1];
    const float* bn_bias   = (const float*)d_in[2];
    const float* bn_mean   = (const float*)d_in[3];
    const float* bn_var    = (const float*)d_in[4];
    const float* W1        = (const float*)d_in[5];
    const float* b1        = (const float*)d_in[6];
    const float* W2        = (const float*)d_in[7];
    const float* b2        = (const float*)d_in[8];
    const int*   receivers = (const int*)d_in[9];
    float*       out       = (float*)d_out;

    const long E = (long)in_sizes[0] / D;
    const int  N = out_size / D;

    const int  nbuck = (N + 127) >> 7;
    const long nblk  = (E + EPB - 1) / EPB;
    const size_t cntBytes  = (size_t)nblk * (size_t)nbuck * 4u;
    const size_t slabBytes = (size_t)nbuck * 128u * D * 4u;
    const size_t baseNeed  = cntBytes + 2u * (size_t)nbuck * 4u + (size_t)E * 4u + 256u;
    const size_t fullNeed  = baseNeed + (size_t)SPLIT * slabBytes;

    if (ws_size < baseNeed || nbuck > 1024 || E >= (1L << 23)) {
        // fallback: direct atomic scatter
        (void)hipMemsetAsync(d_out, 0, (size_t)out_size * sizeof(float), stream);
        const long blocks = (E + (long)(ABLK * EPT) - 1) / (long)(ABLK * EPT);
        edge_mlp_scatter<<<dim3((unsigned)blocks), dim3(ABLK), 0, stream>>>(
            edges, bn_scale, bn_bias, bn_mean, bn_var, W1, b1, W2, b2,
            receivers, out, E);
        return;
    }

    const int S = (ws_size >= fullNeed) ? SPLIT : 1;

    char* w = (char*)d_ws;
    int* cnt    = (int*)w;            w += cntBytes;
    int* totals = (int*)w;            w += (size_t)nbuck * 4u;
    int* basep  = (int*)w;            w += (size_t)nbuck * 4u;
    unsigned int* sorted = (unsigned int*)w;  w += (size_t)E * 4u;
    float* part = (S > 1) ? (float*)(((uintptr_t)w + 255u) & ~(uintptr_t)255u) : nullptr;

    const size_t lds = (size_t)nbuck * 4u;
    const long total = (long)N * D;
    const long slab  = (long)nbuck * 128 * D;

    passA_hist    <<<dim3((unsigned)nblk), dim3(ABLK), lds, stream>>>(receivers, E, nbuck, cnt);
    passS1_colscan<<<dim3((unsigned)nbuck), dim3(SBLK), 0, stream>>>(cnt, (int)nblk, nbuck, totals);
    passS2_basescan<<<dim3(1), dim3(1024), 0, stream>>>(totals, basep, nbuck);
    passB_scatter <<<dim3((unsigned)nblk), dim3(ABLK), lds, stream>>>(receivers, E, nbuck, cnt, basep, sorted);
    passC_gather  <<<dim3((unsigned)nbuck, (unsigned)S), dim3(CBLK), 0, stream>>>(
        edges, sorted, basep, totals,
        bn_scale, bn_bias, bn_mean, bn_var, W1, b1, W2, b2,
        part, out, total, slab);
    if (S > 1) {
        const long total4 = total / 4;
        const long rblocks = (total4 + CBLK - 1) / CBLK;
        reduce_partials<<<dim3((unsigned)rblocks), dim3(CBLK), 0, stream>>>(
            part, out, total4, slab / 4, S);
    }
}

// Round 5
// 564.312 us; speedup vs baseline: 2.7677x; 2.7677x over previous
//
#include <hip/hip_runtime.h>

#define D     12
#define ASTR  13     // LDS acc stride (coprime with 32 banks; 12 -> only 8 banks)
#define EPB   16384  // edges per block for passes A/B
#define ABLK  256
#define SBLK  256
#define CBLK  256
#define SPLIT 4      // blocks per bucket in pass C

// ---------------- pass A: per-block bucket histogram ----------------
__global__ __launch_bounds__(ABLK) void passA_hist(
    const int* __restrict__ receivers, long E, int nbuck,
    int* __restrict__ cnt /* [nblk][nbuck], row-major */)
{
    extern __shared__ int hist[]; // nbuck ints
    for (int i = threadIdx.x; i < nbuck; i += ABLK) hist[i] = 0;
    __syncthreads();
    long e0 = (long)blockIdx.x * EPB;
    long e1 = e0 + EPB; if (e1 > E) e1 = E;
    for (long e = e0 + threadIdx.x; e < e1; e += ABLK) {
        int r = receivers[e];
        atomicAdd(&hist[r >> 7], 1);
    }
    __syncthreads();
    int* row = cnt + (long)blockIdx.x * nbuck;
    for (int i = threadIdx.x; i < nbuck; i += ABLK) row[i] = hist[i];
}

// ---------------- pass S1: exclusive scan down each bucket column ----------------
__global__ __launch_bounds__(SBLK) void passS1_colscan(
    int* __restrict__ cnt, int nblk, int nbuck, int* __restrict__ totals)
{
    int b = blockIdx.x;
    int t = threadIdx.x;
    __shared__ int csum[SBLK];
    int per = (nblk + SBLK - 1) / SBLK;
    int i0 = t * per;
    int i1 = i0 + per; if (i1 > nblk) i1 = nblk;
    int s = 0;
    for (int i = i0; i < i1; ++i) s += cnt[(long)i * nbuck + b];
    csum[t] = s;
    __syncthreads();
    for (int off = 1; off < SBLK; off <<= 1) {
        int add = (t >= off) ? csum[t - off] : 0;
        __syncthreads();
        csum[t] += add;
        __syncthreads();
    }
    int run = csum[t] - s; // exclusive prefix of this thread's chunk
    for (int i = i0; i < i1; ++i) {
        long a = (long)i * nbuck + b;
        int tmp = cnt[a];
        cnt[a] = run;
        run += tmp;
    }
    if (t == SBLK - 1) totals[b] = csum[SBLK - 1];
}

// ---------------- pass S2: exclusive scan over bucket totals ----------------
__global__ __launch_bounds__(1024) void passS2_basescan(
    const int* __restrict__ totals, int* __restrict__ base, int nbuck)
{
    __shared__ int sh[1024];
    int t = threadIdx.x;
    int v = (t < nbuck) ? totals[t] : 0;
    sh[t] = v;
    __syncthreads();
    for (int off = 1; off < 1024; off <<= 1) {
        int add = (t >= off) ? sh[t - off] : 0;
        __syncthreads();
        sh[t] += add;
        __syncthreads();
    }
    if (t < nbuck) base[t] = sh[t] - v;
}

// ---------------- pass B: scatter edge ids into bucket-sorted order ----------------
__global__ __launch_bounds__(ABLK) void passB_scatter(
    const int* __restrict__ receivers, long E, int nbuck,
    const int* __restrict__ cnt, const int* __restrict__ base,
    unsigned int* __restrict__ sorted)
{
    extern __shared__ int cur[]; // nbuck cursors
    const int* row = cnt + (long)blockIdx.x * nbuck;
    for (int i = threadIdx.x; i < nbuck; i += ABLK) cur[i] = row[i] + base[i];
    __syncthreads();
    long e0 = (long)blockIdx.x * EPB;
    long e1 = e0 + EPB; if (e1 > E) e1 = E;
    for (long e = e0 + threadIdx.x; e < e1; e += ABLK) {
        int r = receivers[e];
        int b = r >> 7;
        int pos = atomicAdd(&cur[b], 1);
        sorted[pos] = ((unsigned)e << 7) | (unsigned)(r & 127);
    }
}

// -------- shared helper: build folded weights into LDS --------
__device__ __forceinline__ void build_weights(
    int t,
    const float* __restrict__ bn_scale, const float* __restrict__ bn_bias,
    const float* __restrict__ bn_mean,  const float* __restrict__ bn_var,
    const float* __restrict__ W1, const float* __restrict__ b1,
    const float* __restrict__ W2, const float* __restrict__ b2,
    float* sW1, float* sW2, float* sB1, float* sB2)
{
    if (t < D * D) {
        int d = t / D;
        float a = bn_scale[d] * rsqrtf(bn_var[d] + 1e-5f);
        sW1[t] = a * W1[t];
        sW2[t] = W2[t];
    }
    if (t < D) {
        float acc = b1[t];
        #pragma unroll
        for (int d = 0; d < D; ++d) {
            float a = bn_scale[d] * rsqrtf(bn_var[d] + 1e-5f);
            float c = bn_bias[d] - bn_mean[d] * a;
            acc += c * W1[d * D + t];
        }
        sB1[t] = acc;
        sB2[t] = b2[t];
    }
}

__device__ __forceinline__ void mlp_accum(
    float4 ra, float4 rb, float4 rc, int rloc,
    const float* sW1, const float* sW2, const float* sB1, const float* sB2,
    float* acc)
{
    float x[D] = {ra.x, ra.y, ra.z, ra.w, rb.x, rb.y, rb.z, rb.w,
                  rc.x, rc.y, rc.z, rc.w};
    float h[D];
    #pragma unroll
    for (int j = 0; j < D; ++j) h[j] = sB1[j];
    #pragma unroll
    for (int d = 0; d < D; ++d) {
        float xd = x[d];
        #pragma unroll
        for (int j = 0; j < D; ++j) h[j] = fmaf(xd, sW1[d * D + j], h[j]);
    }
    #pragma unroll
    for (int j = 0; j < D; ++j) h[j] = fmaxf(h[j], 0.f);

    float y[D];
    #pragma unroll
    for (int j = 0; j < D; ++j) y[j] = sB2[j];
    #pragma unroll
    for (int d = 0; d < D; ++d) {
        float hd = h[d];
        #pragma unroll
        for (int j = 0; j < D; ++j) y[j] = fmaf(hd, sW2[d * D + j], y[j]);
    }
    #pragma unroll
    for (int j = 0; j < D; ++j) atomicAdd(&acc[rloc * ASTR + j], y[j]);
}

// ---------------- pass C: per-(bucket,split) pipelined gather + fused MLP ----------------
// Software pipeline: sorted word prefetched 2 iters ahead, edge row 1 iter ahead.
// NO launch_bounds min-occupancy hint — round 4 showed it forces spills (VGPR 64,
// FETCH 489MB->3.96GB of scratch traffic).
__global__ __launch_bounds__(CBLK) void passC_gather(
    const float* __restrict__ edges,
    const unsigned int* __restrict__ sorted,
    const int* __restrict__ base, const int* __restrict__ totals,
    const float* __restrict__ bn_scale, const float* __restrict__ bn_bias,
    const float* __restrict__ bn_mean,  const float* __restrict__ bn_var,
    const float* __restrict__ W1, const float* __restrict__ b1,
    const float* __restrict__ W2, const float* __restrict__ b2,
    float* __restrict__ part,   // null => write out directly
    float* __restrict__ out,
    long total /* N*D */, long slab /* floats per split slab */)
{
    __shared__ float sW1[D * D];
    __shared__ float sW2[D * D];
    __shared__ float sB1[D];
    __shared__ float sB2[D];
    __shared__ float acc[128 * ASTR];

    const int t = threadIdx.x;
    build_weights(t, bn_scale, bn_bias, bn_mean, bn_var, W1, b1, W2, b2,
                  sW1, sW2, sB1, sB2);
    for (int i = t; i < 128 * ASTR; i += CBLK) acc[i] = 0.f;
    __syncthreads();

    const int b = blockIdx.x;
    const int s = blockIdx.y;
    const int S = gridDim.y;
    const int s0 = base[b];
    const int n  = totals[b];
    const int chunk = (n + S - 1) / S;
    const int k0 = s * chunk;
    int k1 = k0 + chunk; if (k1 > n) k1 = n;

    int k = k0 + t;
    if (k < k1) {
        const int kmax = k1 - 1;
        // pipeline prologue
        unsigned sv0 = sorted[s0 + k];
        int kn = k + CBLK; if (kn > kmax) kn = kmax;
        unsigned sv1 = sorted[s0 + kn];
        const float4* p0 = reinterpret_cast<const float4*>(edges + (long)(sv0 >> 7) * D);
        float4 r0a = p0[0], r0b = p0[1], r0c = p0[2];

        for (; k < k1; k += CBLK) {
            // prefetch sorted 2 ahead, row 1 ahead (clamped; duplicates harmless)
            int k2 = k + 2 * CBLK; if (k2 > kmax) k2 = kmax;
            unsigned sv2 = sorted[s0 + k2];
            const float4* p1 = reinterpret_cast<const float4*>(edges + (long)(sv1 >> 7) * D);
            float4 r1a = p1[0], r1b = p1[1], r1c = p1[2];

            mlp_accum(r0a, r0b, r0c, (int)(sv0 & 127u), sW1, sW2, sB1, sB2, acc);

            sv0 = sv1; sv1 = sv2;
            r0a = r1a; r0b = r1b; r0c = r1c;
        }
    }
    __syncthreads();

    if (part != nullptr) {
        float* dst = part + (long)s * slab + (long)b * (128 * D);
        for (int i = t; i < 128 * D; i += CBLK) dst[i] = acc[(i / D) * ASTR + (i % D)];
    } else {
        long obase = (long)b * (128 * D);
        long cnt_w = total - obase; if (cnt_w > 128 * D) cnt_w = 128 * D;
        for (long i = t; i < cnt_w; i += CBLK) out[obase + i] = acc[(i / D) * ASTR + (i % D)];
    }
}

// ---------------- reduce: sum SPLIT partial slabs (float4) ----------------
__global__ __launch_bounds__(CBLK) void reduce_partials(
    const float* __restrict__ part, float* __restrict__ out,
    long total4 /* total/4 */, long slab4 /* slab/4 */, int S)
{
    long i = (long)blockIdx.x * CBLK + threadIdx.x;
    if (i >= total4) return;
    const float4* p = reinterpret_cast<const float4*>(part);
    float4 v = p[i];
    for (int s = 1; s < S; ++s) {
        float4 w = p[(long)s * slab4 + i];
        v.x += w.x; v.y += w.y; v.z += w.z; v.w += w.w;
    }
    reinterpret_cast<float4*>(out)[i] = v;
}

// ---------------- fallback: direct atomic scatter (round-1 kernel) ----------------
#define EPT 4
__global__ __launch_bounds__(ABLK) void edge_mlp_scatter(
    const float* __restrict__ edges,
    const float* __restrict__ bn_scale, const float* __restrict__ bn_bias,
    const float* __restrict__ bn_mean,  const float* __restrict__ bn_var,
    const float* __restrict__ W1, const float* __restrict__ b1,
    const float* __restrict__ W2, const float* __restrict__ b2,
    const int* __restrict__ receivers, float* __restrict__ out, long E)
{
    __shared__ float sW1[D * D], sW2[D * D], sB1[D], sB2[D];
    const int t = threadIdx.x;
    build_weights(t, bn_scale, bn_bias, bn_mean, bn_var, W1, b1, W2, b2,
                  sW1, sW2, sB1, sB2);
    __syncthreads();
    const long basee = (long)blockIdx.x * (ABLK * EPT) + t;
    float x[EPT][D]; int rcv[EPT]; bool valid[EPT];
    #pragma unroll
    for (int kk = 0; kk < EPT; ++kk) {
        long e = basee + (long)kk * ABLK;
        valid[kk] = (e < E); rcv[kk] = 0;
        if (valid[kk]) {
            rcv[kk] = receivers[e];
            const float4* p = reinterpret_cast<const float4*>(edges + e * D);
            float4 v0 = p[0], v1 = p[1], v2 = p[2];
            x[kk][0]=v0.x; x[kk][1]=v0.y; x[kk][2]=v0.z; x[kk][3]=v0.w;
            x[kk][4]=v1.x; x[kk][5]=v1.y; x[kk][6]=v1.z; x[kk][7]=v1.w;
            x[kk][8]=v2.x; x[kk][9]=v2.y; x[kk][10]=v2.z; x[kk][11]=v2.w;
        } else {
            #pragma unroll
            for (int d = 0; d < D; ++d) x[kk][d] = 0.f;
        }
    }
    float h[EPT][D];
    #pragma unroll
    for (int j = 0; j < D; ++j) {
        float bj = sB1[j];
        #pragma unroll
        for (int kk = 0; kk < EPT; ++kk) h[kk][j] = bj;
    }
    #pragma unroll
    for (int d = 0; d < D; ++d) {
        #pragma unroll
        for (int j = 0; j < D; ++j) {
            float w = sW1[d * D + j];
            #pragma unroll
            for (int kk = 0; kk < EPT; ++kk) h[kk][j] = fmaf(x[kk][d], w, h[kk][j]);
        }
    }
    #pragma unroll
    for (int j = 0; j < D; ++j) {
        #pragma unroll
        for (int kk = 0; kk < EPT; ++kk) h[kk][j] = fmaxf(h[kk][j], 0.f);
    }
    #pragma unroll
    for (int j = 0; j < D; ++j) {
        float a2[EPT]; float bj = sB2[j];
        #pragma unroll
        for (int kk = 0; kk < EPT; ++kk) a2[kk] = bj;
        #pragma unroll
        for (int d = 0; d < D; ++d) {
            float w = sW2[d * D + j];
            #pragma unroll
            for (int kk = 0; kk < EPT; ++kk) a2[kk] = fmaf(h[kk][d], w, a2[kk]);
        }
        #pragma unroll
        for (int kk = 0; kk < EPT; ++kk)
            if (valid[kk]) atomicAdd(&out[(long)rcv[kk] * D + j], a2[kk]);
    }
}

extern "C" void kernel_launch(void* const* d_in, const int* in_sizes, int n_in,
                              void* d_out, int out_size, void* d_ws, size_t ws_size,
                              hipStream_t stream) {
    const float* edges     = (const float*)d_in[0];
    const float* bn_scale  = (const float*)d_in[1];
    const float* bn_bias   = (const float*)d_in[2];
    const float* bn_mean   = (const float*)d_in[3];
    const float* bn_var    = (const float*)d_in[4];
    const float* W1        = (const float*)d_in[5];
    const float* b1        = (const float*)d_in[6];
    const float* W2        = (const float*)d_in[7];
    const float* b2        = (const float*)d_in[8];
    const int*   receivers = (const int*)d_in[9];
    float*       out       = (float*)d_out;

    const long E = (long)in_sizes[0] / D;
    const int  N = out_size / D;

    const int  nbuck = (N + 127) >> 7;
    const long nblk  = (E + EPB - 1) / EPB;
    const size_t cntBytes  = (size_t)nblk * (size_t)nbuck * 4u;
    const size_t slabBytes = (size_t)nbuck * 128u * D * 4u;
    const size_t baseNeed  = cntBytes + 2u * (size_t)nbuck * 4u + (size_t)E * 4u + 256u;
    const size_t fullNeed  = baseNeed + (size_t)SPLIT * slabBytes + 256u;

    if (ws_size < baseNeed || nbuck > 1024 || E >= (1L << 23)) {
        // fallback: direct atomic scatter
        (void)hipMemsetAsync(d_out, 0, (size_t)out_size * sizeof(float), stream);
        const long blocks = (E + (long)(ABLK * EPT) - 1) / (long)(ABLK * EPT);
        edge_mlp_scatter<<<dim3((unsigned)blocks), dim3(ABLK), 0, stream>>>(
            edges, bn_scale, bn_bias, bn_mean, bn_var, W1, b1, W2, b2,
            receivers, out, E);
        return;
    }

    const int S = (ws_size >= fullNeed) ? SPLIT : 1;

    char* w = (char*)d_ws;
    int* cnt    = (int*)w;            w += cntBytes;
    int* totals = (int*)w;            w += (size_t)nbuck * 4u;
    int* basep  = (int*)w;            w += (size_t)nbuck * 4u;
    unsigned int* sorted = (unsigned int*)w;  w += (size_t)E * 4u;
    float* part = (S > 1) ? (float*)(((uintptr_t)w + 255u) & ~(uintptr_t)255u) : nullptr;

    const size_t lds = (size_t)nbuck * 4u;
    const long total = (long)N * D;
    const long slab  = (long)nbuck * 128 * D;

    passA_hist    <<<dim3((unsigned)nblk), dim3(ABLK), lds, stream>>>(receivers, E, nbuck, cnt);
    passS1_colscan<<<dim3((unsigned)nbuck), dim3(SBLK), 0, stream>>>(cnt, (int)nblk, nbuck, totals);
    passS2_basescan<<<dim3(1), dim3(1024), 0, stream>>>(totals, basep, nbuck);
    passB_scatter <<<dim3((unsigned)nblk), dim3(ABLK), lds, stream>>>(receivers, E, nbuck, cnt, basep, sorted);
    passC_gather  <<<dim3((unsigned)nbuck, (unsigned)S), dim3(CBLK), 0, stream>>>(
        edges, sorted, basep, totals,
        bn_scale, bn_bias, bn_mean, bn_var, W1, b1, W2, b2,
        part, out, total, slab);
    if (S > 1) {
        const long total4 = total / 4;
        const long rblocks = (total4 + CBLK - 1) / CBLK;
        reduce_partials<<<dim3((unsigned)rblocks), dim3(CBLK), 0, stream>>>(
            part, out, total4, slab / 4, S);
    }
}